// Round 12
// baseline (130.235 us; speedup 1.0000x reference)
//
#include <hip/hip_runtime.h>

// Integrator (scaling & squaring) for vel [16,2,512,512] f32, with logdet-Jacobian.
// Decoupled schedule (ldjac_k and disp_{k+1} share ONE sample position) with
// PACKED 8B records: rec = (disp.y, disp.x, ldjac, pad) as f16x4. Per pixel:
// 1 stream load + 4 gathers + 1 store (was 12 VMEM). 8 dispatches:
// INIT_FUSED -> 6x step_full -> FINAL. XCD-remapped everywhere.
// Buffers: A = d_out raw bytes (32MB), B = ws (32MB). FINAL: B -> planar f32 d_out.

#define NB 16
#define HH 512
#define WW 512
#define HW (HH * WW)          // 262144 = 1<<18
#define TOT (NB * HW)         // 4194304
#define EPS 0.0078125f        // 2^-7
#define DISP_ELEMS (NB * 2 * HW)   // 8388608 (f32 elems of final planar disp)
#define SC (512.0f / 511.0f)

typedef _Float16 f16;
typedef _Float16 f16x4 __attribute__((ext_vector_type(4)));

struct Samp {
    int i00, i01, i10, i11;   // clamped plane offsets (y*W+x)
    float w00, w01, w10, w11; // bilinear weights with OOB folded to 0
};

__device__ __forceinline__ Samp make_samp(float sy, float sx) {
    float fy = floorf(sy), fx = floorf(sx);
    float wy = sy - fy, wx = sx - fx;
    int y0 = (int)fy, x0 = (int)fx;
    int y1 = y0 + 1, x1 = x0 + 1;
    bool xv0 = (unsigned)x0 < (unsigned)WW;
    bool xv1 = (unsigned)x1 < (unsigned)WW;
    bool yv0 = (unsigned)y0 < (unsigned)HH;
    bool yv1 = (unsigned)y1 < (unsigned)HH;
    int xc0 = min(max(x0, 0), WW - 1), xc1 = min(max(x1, 0), WW - 1);
    int yc0 = min(max(y0, 0), HH - 1), yc1 = min(max(y1, 0), HH - 1);
    Samp s;
    s.i00 = yc0 * WW + xc0; s.i01 = yc0 * WW + xc1;
    s.i10 = yc1 * WW + xc0; s.i11 = yc1 * WW + xc1;
    float omwx = 1.0f - wx, omwy = 1.0f - wy;
    s.w00 = (xv0 && yv0) ? omwx * omwy : 0.0f;
    s.w01 = (xv1 && yv0) ? wx * omwy   : 0.0f;
    s.w10 = (xv0 && yv1) ? omwx * wy   : 0.0f;
    s.w11 = (xv1 && yv1) ? wx * wy     : 0.0f;
    return s;
}

// XCD-remapped index: XCD c (= bid&7 under round-robin dispatch) owns tasks
// [c*2048,(c+1)*2048) = images {2c,2c+1}, rows ascending.
__device__ __forceinline__ int remap_idx() {
    int bid = blockIdx.x;
    int task = ((bid & 7) << 11) | (bid >> 3);
    return task * 256 + threadIdx.x;
}

// emulate the fp16 store+load rounding of disp0 = eps*v
__device__ __forceinline__ float rnd16(float v) { return (float)(f16)v; }

// INIT_FUSED: ldjac0 (sobel logdet series) + disp1 (corners gathered from vel,
// fp16 rounding of disp0 emulated). Writes packed record (disp1, ldjac0).
__global__ void __launch_bounds__(256) init_fused(const float* __restrict__ vel,
                                                  f16x4* __restrict__ rdst) {
    int idx = remap_idx();
    int n = idx >> 18;
    int rem = idx & (HW - 1);
    int y = rem >> 9, x = rem & (WW - 1);

    const float* v0 = vel + (size_t)n * 2 * HW;  // vel_y
    const float* v1 = v0 + HW;                   // vel_x

    // ---- sobel jacobian + logdet series (ldjac0) ----
    int ym = max(y - 1, 0), yp = min(y + 1, HH - 1);
    int xm = max(x - 1, 0), xp = min(x + 1, WW - 1);
    int rmm = ym * WW + xm, rm0 = ym * WW + x, rmp = ym * WW + xp;
    int r0m = y * WW + xm,  r00 = y * WW + x,  r0p = y * WW + xp;
    int rpm = yp * WW + xm, rp0 = yp * WW + x, rpp = yp * WW + xp;

    float a, b, c, d;
    {
        float tmm = v0[rmm], tm0 = v0[rm0], tmp = v0[rmp];
        float t0m = v0[r0m],                t0p = v0[r0p];
        float tpm = v0[rpm], tp0 = v0[rp0], tpp = v0[rpp];
        a = 0.125f * ((tpm + 2.0f * tp0 + tpp) - (tmm + 2.0f * tm0 + tmp));
        b = 0.125f * ((tmp + 2.0f * t0p + tpp) - (tmm + 2.0f * t0m + tpm));
    }
    {
        float tmm = v1[rmm], tm0 = v1[rm0], tmp = v1[rmp];
        float t0m = v1[r0m],                t0p = v1[r0p];
        float tpm = v1[rpm], tp0 = v1[rp0], tpp = v1[rpp];
        c = 0.125f * ((tpm + 2.0f * tp0 + tpp) - (tmm + 2.0f * tm0 + tmp));
        d = 0.125f * ((tmp + 2.0f * t0p + tpp) - (tmm + 2.0f * t0m + tpm));
    }

    float xa = a, xb = b, xc = c, xd = d;
    float ld = EPS * (xa + xd);
    float na = xa * a + xb * c, nb = xa * b + xb * d;
    float nc = xc * a + xd * c, nd = xc * b + xd * d;
    xa = na; xb = nb; xc = nc; xd = nd;
    ld -= (EPS * EPS) * (xa + xd) * 0.5f;
    na = xa * a + xb * c; nb = xa * b + xb * d;
    nc = xc * a + xd * c; nd = xc * b + xd * d;
    xa = na; xb = nb; xc = nc; xd = nd;
    ld += (EPS * EPS * EPS) * (xa + xd) * (1.0f / 3.0f);
    na = xa * a + xb * c;
    nd = xc * b + xd * d;
    ld -= (EPS * EPS * EPS * EPS) * (na + nd) * 0.25f;

    // ---- first disp step, corners gathered from vel ----
    float d0 = rnd16(EPS * v0[r00]);
    float d1 = rnd16(EPS * v1[r00]);

    float sy = fmaf((float)y + d0, SC, -0.5f);
    float sx = fmaf((float)x + d1, SC, -0.5f);
    Samp s = make_samp(sy, sx);

    float g00x = rnd16(EPS * v0[s.i00]), g00y = rnd16(EPS * v1[s.i00]);
    float g01x = rnd16(EPS * v0[s.i01]), g01y = rnd16(EPS * v1[s.i01]);
    float g10x = rnd16(EPS * v0[s.i10]), g10y = rnd16(EPS * v1[s.i10]);
    float g11x = rnd16(EPS * v0[s.i11]), g11y = rnd16(EPS * v1[s.i11]);

    float nd0 = d0 + s.w00 * g00x + s.w01 * g01x + s.w10 * g10x + s.w11 * g11x;
    float nd1 = d1 + s.w00 * g00y + s.w01 * g01y + s.w10 * g10y + s.w11 * g11y;

    f16x4 rec;
    rec.x = (f16)nd0; rec.y = (f16)nd1; rec.z = (f16)ld; rec.w = (f16)0.0f;
    rdst[(size_t)n * HW + rem] = rec;
}

// K2..K7: disp_{k+1} AND ldjac_k, both sampled at phi(p, disp_k(p)).
// 1 packed stream load, 4 packed gathers, 1 packed store.
__global__ void __launch_bounds__(256) step_full(const f16x4* __restrict__ rsrc,
                                                 f16x4* __restrict__ rdst) {
    int idx = remap_idx();
    int n = idx >> 18;
    int rem = idx & (HW - 1);
    int y = rem >> 9, x = rem & (WW - 1);

    const f16x4* rp = rsrc + (size_t)n * HW;

    f16x4 rv = rp[rem];
    float d0 = (float)rv.x, d1 = (float)rv.y, l = (float)rv.z;

    float sy = fmaf((float)y + d0, SC, -0.5f);
    float sx = fmaf((float)x + d1, SC, -0.5f);
    Samp s = make_samp(sy, sx);

    f16x4 g00 = rp[s.i00], g01 = rp[s.i01], g10 = rp[s.i10], g11 = rp[s.i11];

    float nd0 = d0 + s.w00 * (float)g00.x + s.w01 * (float)g01.x
                   + s.w10 * (float)g10.x + s.w11 * (float)g11.x;
    float nd1 = d1 + s.w00 * (float)g00.y + s.w01 * (float)g01.y
                   + s.w10 * (float)g10.y + s.w11 * (float)g11.y;
    float nl  = l  + s.w00 * (float)g00.z + s.w01 * (float)g01.z
                   + s.w10 * (float)g10.z + s.w11 * (float)g11.z;

    f16x4 w;
    w.x = (f16)nd0; w.y = (f16)nd1; w.z = (f16)nl; w.w = (f16)0.0f;
    rdst[(size_t)n * HW + rem] = w;
}

// FINAL: ldjac update #7 from streamed disp_7 (records hold disp_7, ldjac_6),
// writes planar f32 disp_7 and f32 ldjac_7.
__global__ void __launch_bounds__(256) step_final(const f16x4* __restrict__ rsrc,
                                                  float* __restrict__ doutp,
                                                  float* __restrict__ loutp) {
    int idx = remap_idx();
    int n = idx >> 18;
    int rem = idx & (HW - 1);
    int y = rem >> 9, x = rem & (WW - 1);

    const f16x4* rp = rsrc + (size_t)n * HW;

    f16x4 rv = rp[rem];
    float d0 = (float)rv.x, d1 = (float)rv.y, l = (float)rv.z;

    float sy = fmaf((float)y + d0, SC, -0.5f);
    float sx = fmaf((float)x + d1, SC, -0.5f);
    Samp s = make_samp(sy, sx);

    f16x4 g00 = rp[s.i00], g01 = rp[s.i01], g10 = rp[s.i10], g11 = rp[s.i11];

    float nl = l + s.w00 * (float)g00.z + s.w01 * (float)g01.z
                 + s.w10 * (float)g10.z + s.w11 * (float)g11.z;

    float* pd = doutp + (size_t)n * 2 * HW;
    pd[rem]      = d0;
    pd[HW + rem] = d1;
    loutp[(size_t)n * HW + rem] = nl;
}

extern "C" void kernel_launch(void* const* d_in, const int* in_sizes, int n_in,
                              void* d_out, int out_size, void* d_ws, size_t ws_size,
                              hipStream_t stream) {
    const float* vel = (const float*)d_in[0];
    float* out = (float*)d_out;

    // Record buffers (32MB each): A = d_out raw bytes, B = ws.
    f16x4* rA = (f16x4*)d_out;
    f16x4* rB = (f16x4*)d_ws;

    dim3 grid(TOT / 256), block(256);     // 16384 blocks, 1 px/thread

    // INIT -> B (disp1, ldjac0)
    // K2: B->A (disp2, ldjac1) ; K3: A->B ; K4: B->A ; K5: A->B ; K6: B->A ; K7: A->B
    // FINAL: B -> d_out planar (disp7 f32, ldjac7 f32)   [overwrites A, unused]
    init_fused<<<grid, block, 0, stream>>>(vel, rB);
    step_full<<<grid, block, 0, stream>>>(rB, rA);
    step_full<<<grid, block, 0, stream>>>(rA, rB);
    step_full<<<grid, block, 0, stream>>>(rB, rA);
    step_full<<<grid, block, 0, stream>>>(rA, rB);
    step_full<<<grid, block, 0, stream>>>(rB, rA);
    step_full<<<grid, block, 0, stream>>>(rA, rB);
    step_final<<<grid, block, 0, stream>>>(rB, out, out + DISP_ELEMS);
}